// Round 3
// baseline (5632.954 us; speedup 1.0000x reference)
//
#include <hip/hip_runtime.h>

typedef _Float16 h8 __attribute__((ext_vector_type(8)));
typedef _Float16 h4 __attribute__((ext_vector_type(4)));
typedef float f32x4 __attribute__((ext_vector_type(4)));

#define NTHREADS 512
#define ROWS 32
#define NBLK 128   // 4096 tokens / 32 rows

// LDS layout (bytes):
//   bufA : 32x1024 fp16 swizzled   at      0  (65536)
//   bufB : 32x1024 fp16 swizzled   at  65536  (65536)
//   Yf   : 32x128  fp32 linear     at 131072  (16384)
//   Yh   : 32x128  fp16 swizzled   at 147456  ( 8192)
#define SMEM_BYTES 155648

__device__ __forceinline__ float fast_tanh(float x) {
    float e = __expf(2.0f * x);
    return 1.0f - 2.0f / (e + 1.0f);
}

// ---- weight fp32 -> fp16 conversion (runs every launch; d_ws is scratch) ----
__global__ void __launch_bounds__(256) cvt_kernel(const float* __restrict__ src,
                                                  _Float16* __restrict__ dst, int n) {
    int i = (blockIdx.x * 256 + threadIdx.x) * 4;
    if (i + 3 < n) {
        f32x4 v = *(const f32x4*)(src + i);
        h4 h;
        h[0] = (_Float16)v[0]; h[1] = (_Float16)v[1];
        h[2] = (_Float16)v[2]; h[3] = (_Float16)v[3];
        *(h4*)(dst + i) = h;
    }
}

// GEMM layer: dst[32][1024] = tanh(src[32][K] @ W^T + bias), all fp16 in LDS (swizzled)
template<int K>
__device__ __forceinline__ void mlp_layer(const char* __restrict__ src, char* __restrict__ dst,
                                          const _Float16* __restrict__ Wh,
                                          const float* __restrict__ bias,
                                          int w, int l15, int lhi)
{
    const int colbase = w * 128;
    f32x4 acc[2][8];
#pragma unroll
    for (int ct = 0; ct < 8; ++ct) {
        float bv = bias[colbase + ct * 16 + l15];
        f32x4 a; a[0] = bv; a[1] = bv; a[2] = bv; a[3] = bv;
        acc[0][ct] = a; acc[1][ct] = a;
    }
    for (int kk = 0; kk < K / 32; ++kk) {
        h8 afrag[2];
#pragma unroll
        for (int rt = 0; rt < 2; ++rt) {
            int row = rt * 16 + l15;
            int byte = (row * (2 * K) + kk * 64 + lhi * 16) ^ ((row & 7) << 4);
            afrag[rt] = *(const h8*)(src + byte);
        }
#pragma unroll
        for (int ct = 0; ct < 8; ++ct) {
            h8 bfrag = *(const h8*)(Wh + (size_t)(colbase + ct * 16 + l15) * K + kk * 32 + lhi * 8);
            acc[0][ct] = __builtin_amdgcn_mfma_f32_16x16x32_f16(afrag[0], bfrag, acc[0][ct], 0, 0, 0);
            acc[1][ct] = __builtin_amdgcn_mfma_f32_16x16x32_f16(afrag[1], bfrag, acc[1][ct], 0, 0, 0);
        }
    }
#pragma unroll
    for (int rt = 0; rt < 2; ++rt)
#pragma unroll
        for (int ct = 0; ct < 8; ++ct)
#pragma unroll
            for (int j = 0; j < 4; ++j) {
                int row = rt * 16 + lhi * 4 + j;
                int g = colbase + ct * 16 + l15;
                float v = fast_tanh(acc[rt][ct][j]);
                int byte = ((row * 1024 + g) * 2) ^ ((row & 7) << 4);
                *(_Float16*)(dst + byte) = (_Float16)v;
            }
}

__global__ void __launch_bounds__(NTHREADS, 2)
node_kernel(const float* __restrict__ y0,
            const float* __restrict__ tarr,
            const float* __restrict__ W_aug,
            const float* __restrict__ b_aug,
            const float* __restrict__ b0,
            const float* __restrict__ b1,
            const float* __restrict__ b2,
            const float* __restrict__ b3,
            const _Float16* __restrict__ W0h,
            const _Float16* __restrict__ W1h,
            const _Float16* __restrict__ W2h,
            const _Float16* __restrict__ W3h,
            float* __restrict__ out)
{
    __shared__ __align__(16) char smem[SMEM_BYTES];
    char* bufA = smem;
    char* bufB = smem + 65536;
    float* Yf  = (float*)(smem + 131072);
    char* Yh   = smem + 147456;

    const int tid  = threadIdx.x;
    const int lane = tid & 63;
    const int w    = tid >> 6;
    const int l15  = lane & 15;
    const int lhi  = lane >> 4;
    const int row0 = blockIdx.x * ROWS;

    const float dtv = tarr[1] - tarr[0];

    // ---- load y0 rows into Yf[:, 0:64] ----
    {
        int idx = tid * 4;          // 512*4 = 2048 = 32*64
        int r = idx >> 6;
        int c = idx & 63;
        f32x4 v = *(const f32x4*)(y0 + (size_t)(row0 + r) * 64 + c);
        *(f32x4*)(Yf + r * 128 + c) = v;
    }
    __syncthreads();

    // ---- augment: Yf[:, 64:128] = y0_row @ W_aug^T + b_aug (fp32 vector) ----
    {
        int idx = tid * 4;
        int r = idx >> 6;
        int a0 = idx & 63;
        float acc0 = b_aug[a0 + 0], acc1 = b_aug[a0 + 1];
        float acc2 = b_aug[a0 + 2], acc3 = b_aug[a0 + 3];
        for (int d = 0; d < 64; ++d) {
            float yv = Yf[r * 128 + d];
            acc0 += yv * W_aug[(a0 + 0) * 64 + d];
            acc1 += yv * W_aug[(a0 + 1) * 64 + d];
            acc2 += yv * W_aug[(a0 + 2) * 64 + d];
            acc3 += yv * W_aug[(a0 + 3) * 64 + d];
        }
        Yf[r * 128 + 64 + a0 + 0] = acc0;
        Yf[r * 128 + 64 + a0 + 1] = acc1;
        Yf[r * 128 + 64 + a0 + 2] = acc2;
        Yf[r * 128 + 64 + a0 + 3] = acc3;
    }
    __syncthreads();

    // ---- build fp16 mirror of Y (swizzled) ----
    auto buildYh = [&]() {
        int idx = tid * 8;          // 512*8 = 4096 = 32*128
        int r = idx >> 7;
        int c = idx & 127;
        const float* p = Yf + r * 128 + c;
        h8 h;
#pragma unroll
        for (int j = 0; j < 8; ++j) h[j] = (_Float16)p[j];
        int byte = ((r * 128 + c) * 2) ^ ((r & 7) << 4);
        *(h8*)(Yh + byte) = h;
    };
    buildYh();
    __syncthreads();

    // ---- 31 Euler steps ----
    for (int s = 0; s < 31; ++s) {
        mlp_layer<128>(Yh, bufA, W0h, b0, w, l15, lhi);
        __syncthreads();
        mlp_layer<1024>(bufA, bufB, W1h, b1, w, l15, lhi);
        __syncthreads();
        mlp_layer<1024>(bufB, bufA, W2h, b2, w, l15, lhi);
        __syncthreads();

        // layer 3: DY[32][128] = bufA @ W3^T + b3 ; Y += dt*DY
        {
            const int g = w * 16 + l15;
            f32x4 acc3[2];
            {
                float bv = b3[g];
                f32x4 a; a[0] = bv; a[1] = bv; a[2] = bv; a[3] = bv;
                acc3[0] = a; acc3[1] = a;
            }
            for (int kk = 0; kk < 32; ++kk) {
                h8 afrag[2];
#pragma unroll
                for (int rt = 0; rt < 2; ++rt) {
                    int row = rt * 16 + l15;
                    int byte = (row * 2048 + kk * 64 + lhi * 16) ^ ((row & 7) << 4);
                    afrag[rt] = *(const h8*)(bufA + byte);
                }
                h8 bfrag = *(const h8*)(W3h + (size_t)g * 1024 + kk * 32 + lhi * 8);
                acc3[0] = __builtin_amdgcn_mfma_f32_16x16x32_f16(afrag[0], bfrag, acc3[0], 0, 0, 0);
                acc3[1] = __builtin_amdgcn_mfma_f32_16x16x32_f16(afrag[1], bfrag, acc3[1], 0, 0, 0);
            }
#pragma unroll
            for (int rt = 0; rt < 2; ++rt)
#pragma unroll
                for (int j = 0; j < 4; ++j) {
                    int row = rt * 16 + lhi * 4 + j;
                    Yf[row * 128 + g] += dtv * acc3[rt][j];
                }
        }
        __syncthreads();
        buildYh();
        __syncthreads();
    }

    // ---- output: out[token][0:64] = Yf[:, 0:64] ----
    {
        int idx = tid * 4;
        int r = idx >> 6;
        int c = idx & 63;
        *(f32x4*)(out + (size_t)(row0 + r) * 64 + c) = *(const f32x4*)(Yf + r * 128 + c);
    }
}

extern "C" void kernel_launch(void* const* d_in, const int* in_sizes, int n_in,
                              void* d_out, int out_size, void* d_ws, size_t ws_size,
                              hipStream_t stream)
{
    const float* y0    = (const float*)d_in[0];
    const float* tarr  = (const float*)d_in[1];
    const float* W_aug = (const float*)d_in[2];
    const float* b_aug = (const float*)d_in[3];
    const float* W0    = (const float*)d_in[4];
    const float* b0    = (const float*)d_in[5];
    const float* W1    = (const float*)d_in[6];
    const float* b1    = (const float*)d_in[7];
    const float* W2    = (const float*)d_in[8];
    const float* b2    = (const float*)d_in[9];
    const float* W3    = (const float*)d_in[10];
    const float* b3    = (const float*)d_in[11];

    _Float16* W0h = (_Float16*)d_ws;            // 1024*128  = 131072
    _Float16* W1h = W0h + 131072;               // 1024*1024 = 1048576
    _Float16* W2h = W1h + 1048576;
    _Float16* W3h = W2h + 1048576;              // 128*1024  = 131072

    cvt_kernel<<<131072 / 1024, 256, 0, stream>>>(W0, W0h, 131072);
    cvt_kernel<<<1048576 / 1024, 256, 0, stream>>>(W1, W1h, 1048576);
    cvt_kernel<<<1048576 / 1024, 256, 0, stream>>>(W2, W2h, 1048576);
    cvt_kernel<<<131072 / 1024, 256, 0, stream>>>(W3, W3h, 131072);

    node_kernel<<<NBLK, NTHREADS, 0, stream>>>(y0, tarr, W_aug, b_aug,
                                               b0, b1, b2, b3,
                                               W0h, W1h, W2h, W3h,
                                               (float*)d_out);
}